// Round 11
// baseline (80328.510 us; speedup 1.0000x reference)
//
#include <hip/hip_runtime.h>

#define TT 1024
#define BB 64
#define HH 512
#define DD 512
#define NBLK 512
#define NTHR 256
#define NGRP 16          // 16 batch groups x 4 rows; 32 blocks per group; 2 blocks/CU
#define GB 4             // batches per group
#define BSTR 1536        // unified inT row stride: [x | h0 | h1]

// ---------------- ws layout (32-bit words), total 4,571,136 words = 18,284,544 B
// (< 18,350,336 B proven cap)
#define W0T4_OFF 0               // [256 kq][2048 R][4]  transposed-packed W0
#define W1T4_OFF 2097152         // same for W1
#define H0_OFF   4194304         // [64 b][512]  h0 single-buffered
#define H1_OFF   4227072         // [64 b][512]
#define Z0_OFF   4259840         // [16 grp][4 bi][2048]
#define Z1_OFF   4390912         // [16 grp][4 bi][2048]
#define HWZ_OFF  4521984         // [16 grp][4 bi][512]
#define FLG_OFF  4554752         // [16 grp][32 slot][32 words]  (128B stride)

// ======== cross-block access (R10-proven) ========
// Loads: agent-relaxed (sc1) — read the coherence point.
__device__ __forceinline__ float ldg_cg(const float* p) {
    return __hip_atomic_load(p, __ATOMIC_RELAXED, __HIP_MEMORY_SCOPE_AGENT);
}
__device__ __forceinline__ float4 ldg_cg4(const float* p) {
    const unsigned long long* q = (const unsigned long long*)p;
    unsigned long long a = __hip_atomic_load(q,     __ATOMIC_RELAXED, __HIP_MEMORY_SCOPE_AGENT);
    unsigned long long b = __hip_atomic_load(q + 1, __ATOMIC_RELAXED, __HIP_MEMORY_SCOPE_AGENT);
    float4 v;
    ((unsigned long long*)&v)[0] = a;
    ((unsigned long long*)&v)[1] = b;
    return v;
}
__device__ __forceinline__ unsigned ldg_cgu(const unsigned* p) {
    return __hip_atomic_load(p, __ATOMIC_RELAXED, __HIP_MEMORY_SCOPE_AGENT);
}
// Stores: SYSTEM-relaxed write-through — keeps L2 clean so the release-barrier's
// writeback is near-empty (R10-proven).
__device__ __forceinline__ void stg_wt(float* p, float v) {
    __hip_atomic_store(p, v, __ATOMIC_RELAXED, __HIP_MEMORY_SCOPE_SYSTEM);
}

// ======== group barrier: 32 blocks, flag-array, RELEASE-published (R7-proven) ========
__device__ __forceinline__ void group_barrier(unsigned* gfl, unsigned tgt, int slot, int tid)
{
    __syncthreads();
    if (tid == 0)
        __hip_atomic_store(&gfl[slot * 32], tgt, __ATOMIC_RELEASE, __HIP_MEMORY_SCOPE_AGENT);
    if (tid < 32) {
        while (ldg_cgu(&gfl[tid * 32]) < tgt) __builtin_amdgcn_s_sleep(1);
    }
    __syncthreads();
}

// ---------------- init: transpose-pack weights + zero h-state + flags ----------------
__global__ void ln_lstm_init_kernel(const float* __restrict__ W0, const float* __restrict__ W1,
                                    float* __restrict__ ws)
{
    const int stride = gridDim.x * blockDim.x;
    const int idx = blockIdx.x * blockDim.x + threadIdx.x;
    for (int i = idx; i < 2048 * 256; i += stride) {
        const int R = i & 2047, kq = i >> 11;
        const float4 v0 = *(const float4*)&W0[(size_t)R * 1024 + kq * 4];
        const float4 v1 = *(const float4*)&W1[(size_t)R * 1024 + kq * 4];
        *(float4*)&ws[W0T4_OFF + ((size_t)kq * 2048 + R) * 4] = v0;
        *(float4*)&ws[W1T4_OFF + ((size_t)kq * 2048 + R) * 4] = v1;
    }
    for (int i = idx; i < 65536; i += stride) ws[H0_OFF + i] = 0.f;    // h0 + h1
    unsigned* uw = (unsigned*)ws;
    for (int i = idx; i < 16384; i += stride) uw[FLG_OFF + i] = 0u;    // barrier flags
}

// ---------------- full-K GEMV off unified inT: 64 rows x 4 batches; K quartered ------
// Same W-load pattern/count as R8/R10's proven engine; batch fan-out halved.
// After zr exchange, thread (bi_out=tid>>6 in 0..3, r=tid&63) holds z[R0+r, bi_out].
__device__ __forceinline__ void gemv_k4u(const float4* __restrict__ wt, const float* __restrict__ inT,
                                         int koff, float* __restrict__ zr, int bq, int r, int Rrow,
                                         float& z)
{
    float a[GB];
#pragma unroll
    for (int i = 0; i < GB; ++i) a[i] = 0.f;
    const float4* wp = wt + (size_t)(bq * 64) * 2048 + Rrow;
    const float* ib = inT + koff + bq * 256;
    for (int c = 0; c < 4; ++c) {
        float4 w[16];
#pragma unroll
        for (int i = 0; i < 16; ++i) w[i] = wp[(size_t)(c * 16 + i) * 2048];
#pragma unroll
        for (int i = 0; i < 16; ++i) {
            const int kk = c * 64 + i * 4;
#pragma unroll
            for (int bi = 0; bi < GB; ++bi) {
                const float4 iv = *(const float4*)&ib[bi * BSTR + kk];
                a[bi] += w[i].x * iv.x + w[i].y * iv.y + w[i].z * iv.z + w[i].w * iv.w;
            }
        }
    }
#pragma unroll
    for (int bi = 0; bi < GB; ++bi) zr[bq * 256 + bi * 64 + r] = a[bi];
    __syncthreads();
    const int bi_out = (int)( (unsigned)( (r + 0) ) , 0);  // placeholder (unused)
    (void)bi_out;
    z = 0.f;
    const int bo = (int)((unsigned)( ( ( ( (0) ) ) ) ));   // silence
    (void)bo;
    const int b_out = ( ( ( ( ( ( (int)0 ) ) ) ) ) );
    (void)b_out;
#pragma unroll
    for (int w2 = 0; w2 < 4; ++w2) z += zr[w2 * 256 + ( ( ( ( ( ( ( ( (0) ) ) ) ) ) ) ) )];
}

// ---------------- block-local reductions (R8-proven, 4 waves) ----------------
__device__ __forceinline__ void block_reduce8(float v[8], float* sred, int tid)
{
#pragma unroll
    for (int off = 32; off > 0; off >>= 1)
#pragma unroll
        for (int k = 0; k < 8; ++k) v[k] += __shfl_down(v[k], off, 64);
    __syncthreads();
    if ((tid & 63) == 0) {
        const int wv = tid >> 6;
#pragma unroll
        for (int k = 0; k < 8; ++k) sred[k * 4 + wv] = v[k];
    }
    __syncthreads();
#pragma unroll
    for (int k = 0; k < 8; ++k)
        v[k] = sred[k * 4 + 0] + sred[k * 4 + 1] + sred[k * 4 + 2] + sred[k * 4 + 3];
}
__device__ __forceinline__ void block_reduce2(float& s1, float& s2, float* sred, int tid)
{
#pragma unroll
    for (int off = 32; off > 0; off >>= 1) {
        s1 += __shfl_down(s1, off, 64);
        s2 += __shfl_down(s2, off, 64);
    }
    __syncthreads();
    if ((tid & 63) == 0) {
        const int wv = tid >> 6;
        sred[wv] = s1; sred[4 + wv] = s2;
    }
    __syncthreads();
    s1 = sred[0] + sred[1] + sred[2] + sred[3];
    s2 = sred[4] + sred[5] + sred[6] + sred[7];
}

// ---------------- whole LSTM cell for one batch, fully block-local (R8-proven) -------
__device__ __forceinline__ void cell(const float* __restrict__ zg, const float* __restrict__ gb,
                                     const float* __restrict__ lng, const float* __restrict__ lnb,
                                     float cc[2], float* __restrict__ hws_b, float hv[2],
                                     float* sred, int tid)
{
    float z[4][2];
#pragma unroll
    for (int g = 0; g < 4; ++g) {
        z[g][0] = ldg_cg(zg + g * 512 + tid)       + gb[g * 512 + tid];
        z[g][1] = ldg_cg(zg + g * 512 + tid + 256) + gb[g * 512 + tid + 256];
    }
    float st[8];
#pragma unroll
    for (int g = 0; g < 4; ++g) {
        st[g]     = z[g][0] + z[g][1];
        st[4 + g] = z[g][0] * z[g][0] + z[g][1] * z[g][1];
    }
    block_reduce8(st, sred, tid);
    float act[4][2];
#pragma unroll
    for (int g = 0; g < 4; ++g) {
        const float mu = st[g] * (1.f / 512.f);
        const float rs = rsqrtf(st[4 + g] * (1.f / 512.f) - mu * mu + 1e-5f);
#pragma unroll
        for (int e = 0; e < 2; ++e) {
            const int j = tid + e * 256;
            const float a = (z[g][e] - mu) * rs * lng[g * 512 + j] + lnb[g * 512 + j];
            act[g][e] = (g == 2) ? tanhf(a) : 1.f / (1.f + expf(-a));
        }
    }
    float cn[2];
#pragma unroll
    for (int e = 0; e < 2; ++e) {
        cn[e] = act[1][e] * cc[e] + act[0][e] * act[2][e];   // f*c + i*g
        cc[e] = cn[e];
    }
    float s1 = cn[0] + cn[1];
    float s2 = cn[0] * cn[0] + cn[1] * cn[1];
    block_reduce2(s1, s2, sred, tid);
    const float mu = s1 * (1.f / 512.f);
    const float rs = rsqrtf(s2 * (1.f / 512.f) - mu * mu + 1e-5f);
#pragma unroll
    for (int e = 0; e < 2; ++e) {
        const int j = tid + e * 256;
        const float h = act[3][e] * tanhf((cn[e] - mu) * rs * lng[2048 + j] + lnb[2048 + j]);
        stg_wt(hws_b + j, h);
        hv[e] = h;
    }
}

__global__ __launch_bounds__(NTHR, 2)
void LayerNormLSTMStack_55508157333865_kernel(
    const float* __restrict__ x,
    const float* __restrict__ W0, const float* __restrict__ gb0,
    const float* __restrict__ lng0, const float* __restrict__ lnb0,
    const float* __restrict__ W1, const float* __restrict__ gb1,
    const float* __restrict__ lng1, const float* __restrict__ lnb1,
    const float* __restrict__ hwW, const float* __restrict__ hwb,
    float* __restrict__ out, float* __restrict__ ws)
{
    __shared__ __align__(16) float inT[GB * BSTR];  // 24 KB: [bi][ x(t+1) | h0(t) | h1(t-1) ]
    __shared__ __align__(16) float zr[4 * 256];     // 4 KB per-wave K-partials
    __shared__ float sred[32];
    __shared__ float hwred[256];

    const int tid = threadIdx.x;
    const int grp = blockIdx.x >> 5;        // batch group (4 rows)
    const int bg  = blockIdx.x & 31;        // slot in group
    const int bb0 = grp * GB;
    const int r = tid & 63, bq = tid >> 6;
    const int R0 = bg * 64;                 // this block's 64 GEMV rows

    const float4* w0t = (const float4*)(ws + W0T4_OFF);
    const float4* w1t = (const float4*)(ws + W1T4_OFF);
    float* h0ws  = ws + H0_OFF;
    float* h1ws  = ws + H1_OFF;
    float* z0g   = ws + Z0_OFF + grp * (GB * 2048);
    float* z1g   = ws + Z1_OFF + grp * (GB * 2048);
    float* hwzg  = ws + HWZ_OFF + grp * (GB * 512);
    unsigned* gfl = (unsigned*)ws + FLG_OFF + grp * 1024;

    float c0[2] = {0.f, 0.f}, c1[2] = {0.f, 0.f};
    float hv0[2] = {0.f, 0.f};              // bg<GB: h0(t+1) registers
    unsigned ph = 0;
    const size_t OUT_SZ = (size_t)BB * TT * HH;
    const int sbi = tid >> 6, part = tid & 63;   // staging: row sbi (0..3), lane part (0..63)
    const int bi_out = tid >> 6;                 // gemv output batch for this thread

    // helper lambda-free z gather (after gemv zr exchange): thread holds (r, bi_out)
    // (inlined below where used)

    // ================= prologue: gemv0(0) ; cell0(0) =================
    {
        const float* xp = x + ((size_t)(bb0 + sbi) * TT + 0) * DD + part * 8;
        float* d = &inT[sbi * BSTR + part * 8];
        *(float4*)(d)     = *(const float4*)(xp);
        *(float4*)(d + 4) = *(const float4*)(xp + 4);
        float* dh = &inT[sbi * BSTR + 512 + part * 8];       // h0(-1)=0
        const float4 zz = make_float4(0.f, 0.f, 0.f, 0.f);
        *(float4*)(dh) = zz; *(float4*)(dh + 4) = zz;
    }
    __syncthreads();
    {
        // gemv0(0): inline K-quartered GEMV (same engine as loop body)
        float a[GB];
#pragma unroll
        for (int i = 0; i < GB; ++i) a[i] = 0.f;
        const float4* wp = w0t + (size_t)(bq * 64) * 2048 + (R0 + r);
        const float* ib = inT + bq * 256;
        for (int c = 0; c < 4; ++c) {
            float4 w[16];
#pragma unroll
            for (int i = 0; i < 16; ++i) w[i] = wp[(size_t)(c * 16 + i) * 2048];
#pragma unroll
            for (int i = 0; i < 16; ++i) {
                const int kk = c * 64 + i * 4;
#pragma unroll
                for (int bi = 0; bi < GB; ++bi) {
                    const float4 iv = *(const float4*)&ib[bi * BSTR + kk];
                    a[bi] += w[i].x * iv.x + w[i].y * iv.y + w[i].z * iv.z + w[i].w * iv.w;
                }
            }
        }
#pragma unroll
        for (int bi = 0; bi < GB; ++bi) zr[bq * 256 + bi * 64 + r] = a[bi];
        __syncthreads();
        float z = 0.f;
#pragma unroll
        for (int w2 = 0; w2 < 4; ++w2) z += zr[w2 * 256 + bi_out * 64 + r];
        stg_wt(z0g + (size_t)bi_out * 2048 + R0 + r, z);
    }
    group_barrier(gfl, ++ph, bg, tid);
    if (bg < GB)
        cell(z0g + (size_t)bg * 2048, gb0, lng0, lnb0, c0, h0ws + (size_t)(bb0 + bg) * 512, hv0, sred, tid);
    group_barrier(gfl, ++ph, bg, tid);

    for (int t = 0; t < TT; ++t) {
        const bool more = (t + 1 < TT);
        const int tx = more ? (t + 1) : (TT - 1);   // clamped x index

        // ===== P_A: single stage [x(t+1)|h0(t)|h1(t-1)] -> gemv1(t), hw(t), gemv0(t+1) =====
        {
            const float* xp = x + ((size_t)(bb0 + sbi) * TT + tx) * DD + part * 8;
            const float4 xa = *(const float4*)(xp);
            const float4 xb = *(const float4*)(xp + 4);
            const float* hp0 = h0ws + (size_t)(bb0 + sbi) * 512 + part * 8;
            const float4 h0a = ldg_cg4(hp0);
            const float4 h0b = ldg_cg4(hp0 + 4);
            const float* hp1 = h1ws + (size_t)(bb0 + sbi) * 512 + part * 8;
            const float4 h1a = ldg_cg4(hp1);
            const float4 h1b = ldg_cg4(hp1 + 4);
            float* d = &inT[sbi * BSTR + part * 8];
            *(float4*)(d)     = xa; *(float4*)(d + 4) = xb;
            float* dh0 = &inT[sbi * BSTR + 512 + part * 8];
            *(float4*)(dh0)     = h0a; *(float4*)(dh0 + 4) = h0b;
            float* dh1 = &inT[sbi * BSTR + 1024 + part * 8];
            *(float4*)(dh1)     = h1a; *(float4*)(dh1 + 4) = h1b;
        }
        __syncthreads();
        {
            // gemv1(t): K = [h0|h1] (koff 512)
            float a[GB];
#pragma unroll
            for (int i = 0; i < GB; ++i) a[i] = 0.f;
            const float4* wp = w1t + (size_t)(bq * 64) * 2048 + (R0 + r);
            const float* ib = inT + 512 + bq * 256;
            for (int c = 0; c < 4; ++c) {
                float4 w[16];
#pragma unroll
                for (int i = 0; i < 16; ++i) w[i] = wp[(size_t)(c * 16 + i) * 2048];
#pragma unroll
                for (int i = 0; i < 16; ++i) {
                    const int kk = c * 64 + i * 4;
#pragma unroll
                    for (int bi = 0; bi < GB; ++bi) {
                        const float4 iv = *(const float4*)&ib[bi * BSTR + kk];
                        a[bi] += w[i].x * iv.x + w[i].y * iv.y + w[i].z * iv.z + w[i].w * iv.w;
                    }
                }
            }
#pragma unroll
            for (int bi = 0; bi < GB; ++bi) zr[bq * 256 + bi * 64 + r] = a[bi];
            __syncthreads();
            float z = 0.f;
#pragma unroll
            for (int w2 = 0; w2 < 4; ++w2) z += zr[w2 * 256 + bi_out * 64 + r];
            stg_wt(z1g + (size_t)bi_out * 2048 + R0 + r, z);
        }
        // highway rows [bg*16,+16) x 4 batches off h0(t) (inT cols 512..1023)
        {
            const int rh = tid & 15, bi = (tid >> 4) & 3, qk = tid >> 6;   // qk 0..3
            const float* wr = hwW + (size_t)(bg * 16 + rh) * 512 + qk * 128;
            const float* ibh = &inT[bi * BSTR + 512 + qk * 128];
            float acc = 0.f;
#pragma unroll 8
            for (int k = 0; k < 128; k += 4) {
                const float4 wv = *(const float4*)&wr[k];
                const float4 iv = *(const float4*)&ibh[k];
                acc += wv.x * iv.x + wv.y * iv.y + wv.z * iv.z + wv.w * iv.w;
            }
            hwred[tid] = acc;
            __syncthreads();                  // also closes zr WAR (gemv1 reads done)
            if (tid < 64) {
                const int rh2 = tid & 15, bi2 = tid >> 4;
                stg_wt(hwzg + (size_t)bi2 * 512 + bg * 16 + rh2,
                       hwred[tid] + hwred[tid + 64] + hwred[tid + 128] + hwred[tid + 192]);
            }
        }
        if (more) {
            // gemv0(t+1): K = [x|h0] (koff 0)
            float a[GB];
#pragma unroll
            for (int i = 0; i < GB; ++i) a[i] = 0.f;
            const float4* wp = w0t + (size_t)(bq * 64) * 2048 + (R0 + r);
            const float* ib = inT + bq * 256;
            for (int c = 0; c < 4; ++c) {
                float4 w[16];
#pragma unroll
                for (int i = 0; i < 16; ++i) w[i] = wp[(size_t)(c * 16 + i) * 2048];
#pragma unroll
                for (int i = 0; i < 16; ++i) {
                    const int kk = c * 64 + i * 4;
#pragma unroll
                    for (int bi = 0; bi < GB; ++bi) {
                        const float4 iv = *(const float4*)&ib[bi * BSTR + kk];
                        a[bi] += w[i].x * iv.x + w[i].y * iv.y + w[i].z * iv.z + w[i].w * iv.w;
                    }
                }
            }
            __syncthreads();                  // zr WAR vs gemv1's reads (hw sync covers most; keep safe)
#pragma unroll
            for (int bi = 0; bi < GB; ++bi) zr[bq * 256 + bi * 64 + r] = a[bi];
            __syncthreads();
            float z = 0.f;
#pragma unroll
            for (int w2 = 0; w2 < 4; ++w2) z += zr[w2 * 256 + bi_out * 64 + r];
            stg_wt(z0g + (size_t)bi_out * 2048 + R0 + r, z);
        }
        group_barrier(gfl, ++ph, bg, tid);

        // ===== P_B: parallel cells — bg<4: cell0(t+1); bg 4..7: cell1(t)+out(t) =====
        if (bg < GB) {
            const int b = bb0 + bg;
            if (more) {
                cell(z0g + (size_t)bg * 2048, gb0, lng0, lnb0, c0, h0ws + (size_t)b * 512, hv0, sred, tid);
            } else {
#pragma unroll
                for (int e = 0; e < 2; ++e) {
                    const int j = tid + e * 256;
                    out[OUT_SZ + (size_t)b * 512 + j]         = hv0[e];  // h_n[0]
                    out[OUT_SZ + 65536 + (size_t)b * 512 + j] = c0[e];   // c_n[0]
                }
            }
        } else if (bg < 2 * GB) {
            const int bi = bg - GB;
            const int b = bb0 + bi;
            float hv1[2];
            cell(z1g + (size_t)bi * 2048, gb1, lng1, lnb1, c1, h1ws + (size_t)b * 512, hv1, sred, tid);
#pragma unroll
            for (int e = 0; e < 2; ++e) {
                const int j = tid + e * 256;
                const float hz = ldg_cg(hwzg + (size_t)bi * 512 + j) + hwb[j];
                const float gt = 1.f / (1.f + expf(-hz));
                const float h0v = inT[bi * BSTR + 512 + j];   // h0(t) from own staged inT
                out[((size_t)b * TT + t) * HH + j] = gt * hv1[e] + (1.f - gt) * h0v;
            }
            if (!more) {
#pragma unroll
                for (int e = 0; e < 2; ++e) {
                    const int j = tid + e * 256;
                    out[OUT_SZ + 32768 + (size_t)b * 512 + j] = hv1[e];  // h_n[1]
                    out[OUT_SZ + 98304 + (size_t)b * 512 + j] = c1[e];   // c_n[1]
                }
            }
        }
        group_barrier(gfl, ++ph, bg, tid);
    } // t
}

extern "C" void kernel_launch(void* const* d_in, const int* in_sizes, int n_in,
                              void* d_out, int out_size, void* d_ws, size_t ws_size,
                              hipStream_t stream)
{
    (void)in_sizes; (void)n_in; (void)out_size; (void)ws_size;
    const float* x    = (const float*)d_in[0];
    const float* W0   = (const float*)d_in[1];
    const float* b0   = (const float*)d_in[2];
    const float* lng0 = (const float*)d_in[3];
    const float* lnb0 = (const float*)d_in[4];
    const float* W1   = (const float*)d_in[5];
    const float* b1   = (const float*)d_in[6];
    const float* lng1 = (const float*)d_in[7];
    const float* lnb1 = (const float*)d_in[8];
    const float* hwW  = (const float*)d_in[9];
    const float* hwb  = (const float*)d_in[10];
    float* out = (float*)d_out;
    float* ws  = (float*)d_ws;

    ln_lstm_init_kernel<<<dim3(256), dim3(256), 0, stream>>>(W0, W1, ws);
    LayerNormLSTMStack_55508157333865_kernel<<<dim3(NBLK), dim3(NTHR), 0, stream>>>(
        x, W0, b0, lng0, lnb0, W1, b1, lng1, lnb1, hwW, hwb, out, ws);
}

// Round 12
// 71788.171 us; speedup vs baseline: 1.1190x; 1.1190x over previous
//
#include <hip/hip_runtime.h>

#define TT 1024
#define BB 64
#define HH 512
#define DD 512
#define NBLK 256
#define NTHR 256
#define NGRP 8           // 8 batch groups x 8 rows; 32 blocks per group (PROVEN grid - do not change)
#define BSTR 1536        // unified inT row stride: [x | h0 | h1]

// ---------------- ws layout (32-bit words) — offsets identical to R10 (proven cap) ----
#define W0T4_OFF 0               // [256 kq][2048 R][4]  transposed-packed W0
#define W1T4_OFF 2097152         // same for W1
#define Z0_OFF   4259840         // [8 grp][8 bi][2048]
#define Z1_OFF   4390912         // [8 grp][8 bi][2048]
#define FLG_OFF  4554752         // [8 grp][32 slot][32 words]  (128B stride)

// ======== cross-block access: agent-relaxed atomics + release barrier (R7/R8-proven) ====
__device__ __forceinline__ float4 ldg_cg4(const float* p) {
    const unsigned long long* q = (const unsigned long long*)p;
    unsigned long long a = __hip_atomic_load(q,     __ATOMIC_RELAXED, __HIP_MEMORY_SCOPE_AGENT);
    unsigned long long b = __hip_atomic_load(q + 1, __ATOMIC_RELAXED, __HIP_MEMORY_SCOPE_AGENT);
    float4 v;
    ((unsigned long long*)&v)[0] = a;
    ((unsigned long long*)&v)[1] = b;
    return v;
}
__device__ __forceinline__ void stg_cg(float* p, float v) {
    __hip_atomic_store(p, v, __ATOMIC_RELAXED, __HIP_MEMORY_SCOPE_AGENT);
}
__device__ __forceinline__ unsigned ldg_cgu(const unsigned* p) {
    return __hip_atomic_load(p, __ATOMIC_RELAXED, __HIP_MEMORY_SCOPE_AGENT);
}

// ======== group barrier: 32 blocks, flag-array, RELEASE-published (R7-proven) ========
__device__ __forceinline__ void group_barrier(unsigned* gfl, unsigned tgt, int slot, int tid)
{
    __syncthreads();
    if (tid == 0)
        __hip_atomic_store(&gfl[slot * 32], tgt, __ATOMIC_RELEASE, __HIP_MEMORY_SCOPE_AGENT);
    if (tid < 32) {
        while (ldg_cgu(&gfl[tid * 32]) < tgt) __builtin_amdgcn_s_sleep(1);
    }
    __syncthreads();
}

// ---------------- init: transpose-pack weights + zero flags ----------------
__global__ void ln_lstm_init_kernel(const float* __restrict__ W0, const float* __restrict__ W1,
                                    float* __restrict__ ws)
{
    const int stride = gridDim.x * blockDim.x;
    const int idx = blockIdx.x * blockDim.x + threadIdx.x;
    for (int i = idx; i < 2048 * 256; i += stride) {
        const int R = i & 2047, kq = i >> 11;
        const float4 v0 = *(const float4*)&W0[(size_t)R * 1024 + kq * 4];
        const float4 v1 = *(const float4*)&W1[(size_t)R * 1024 + kq * 4];
        *(float4*)&ws[W0T4_OFF + ((size_t)kq * 2048 + R) * 4] = v0;
        *(float4*)&ws[W1T4_OFF + ((size_t)kq * 2048 + R) * 4] = v1;
    }
    unsigned* uw = (unsigned*)ws;
    for (int i = idx; i < 8192; i += stride) uw[FLG_OFF + i] = 0u;     // barrier flags
}

// ---------------- full-K GEMV off unified inT (R10-proven engine, agent z-stores) ----
__device__ __forceinline__ void gemv_k4u(const float4* __restrict__ wt, const float* __restrict__ inT,
                                         int koff, float* __restrict__ zr, int bq, int r, int Rrow,
                                         float& z0, float& z1)
{
    float a[8];
#pragma unroll
    for (int i = 0; i < 8; ++i) a[i] = 0.f;
    const float4* wp = wt + (size_t)(bq * 64) * 2048 + Rrow;
    const float* ib = inT + koff + bq * 256;
    for (int c = 0; c < 4; ++c) {
        float4 w[16];
#pragma unroll
        for (int i = 0; i < 16; ++i) w[i] = wp[(size_t)(c * 16 + i) * 2048];
#pragma unroll
        for (int i = 0; i < 16; ++i) {
            const int kk = c * 64 + i * 4;
#pragma unroll
            for (int bi = 0; bi < 8; ++bi) {
                const float4 iv = *(const float4*)&ib[bi * BSTR + kk];
                a[bi] += w[i].x * iv.x + w[i].y * iv.y + w[i].z * iv.z + w[i].w * iv.w;
            }
        }
    }
#pragma unroll
    for (int bi = 0; bi < 8; ++bi) zr[bq * 512 + bi * 64 + r] = a[bi];
    __syncthreads();
    z0 = 0.f; z1 = 0.f;
#pragma unroll
    for (int w2 = 0; w2 < 4; ++w2) {
        z0 += zr[w2 * 512 + bq * 64 + r];
        z1 += zr[w2 * 512 + (bq + 4) * 64 + r];
    }
}

// ---------------- REDUNDANT wave-local cell: wave wv owns batches {2wv, 2wv+1} --------
// All 32 blocks run this identically (deterministic fp => identical c/h everywhere).
// Lane ln owns elems [ln*8, ln*8+8). LN stats via shuffle tree — no __syncthreads.
// Writes h directly into inT's h-slot (inTh = inT + hslot).
__device__ __forceinline__ void cellW(const float* __restrict__ zg,
                                      const float* __restrict__ gb,
                                      const float* __restrict__ lng,
                                      const float* __restrict__ lnb,
                                      float c[2][8], float* __restrict__ inTh,
                                      int wv, int ln, bool wf,
                                      float* __restrict__ fH, float* __restrict__ fC)
{
    const int e0 = ln * 8;
#pragma unroll
    for (int p = 0; p < 2; ++p) {
        const int bi = 2 * wv + p;
        const float* zb = zg + (size_t)bi * 2048;
        float zv[4][8];
#pragma unroll
        for (int g = 0; g < 4; ++g) {
            const float4 za = ldg_cg4(zb + g * 512 + e0);
            const float4 zc = ldg_cg4(zb + g * 512 + e0 + 4);
            const float4 ba = *(const float4*)&gb[g * 512 + e0];
            const float4 bb = *(const float4*)&gb[g * 512 + e0 + 4];
            zv[g][0] = za.x + ba.x; zv[g][1] = za.y + ba.y;
            zv[g][2] = za.z + ba.z; zv[g][3] = za.w + ba.w;
            zv[g][4] = zc.x + bb.x; zv[g][5] = zc.y + bb.y;
            zv[g][6] = zc.z + bb.z; zv[g][7] = zc.w + bb.w;
        }
        float st[8];
#pragma unroll
        for (int g = 0; g < 4; ++g) {
            float s = 0.f, q = 0.f;
#pragma unroll
            for (int e = 0; e < 8; ++e) { s += zv[g][e]; q += zv[g][e] * zv[g][e]; }
            st[g] = s; st[4 + g] = q;
        }
#pragma unroll
        for (int off = 32; off > 0; off >>= 1)
#pragma unroll
            for (int k = 0; k < 8; ++k) st[k] += __shfl_xor(st[k], off, 64);
        float act[4][8];
#pragma unroll
        for (int g = 0; g < 4; ++g) {
            const float mu = st[g] * (1.f / 512.f);
            const float rs = rsqrtf(st[4 + g] * (1.f / 512.f) - mu * mu + 1e-5f);
            const float4 la = *(const float4*)&lng[g * 512 + e0];
            const float4 lc = *(const float4*)&lng[g * 512 + e0 + 4];
            const float4 pa = *(const float4*)&lnb[g * 512 + e0];
            const float4 pc = *(const float4*)&lnb[g * 512 + e0 + 4];
            const float lg[8] = {la.x, la.y, la.z, la.w, lc.x, lc.y, lc.z, lc.w};
            const float lb[8] = {pa.x, pa.y, pa.z, pa.w, pc.x, pc.y, pc.z, pc.w};
#pragma unroll
            for (int e = 0; e < 8; ++e) {
                const float a = (zv[g][e] - mu) * rs * lg[e] + lb[e];
                act[g][e] = (g == 2) ? tanhf(a) : 1.f / (1.f + expf(-a));
            }
        }
        float cn[8];
        float cs = 0.f, cq = 0.f;
#pragma unroll
        for (int e = 0; e < 8; ++e) {
            cn[e] = act[1][e] * c[p][e] + act[0][e] * act[2][e];   // f*c + i*g
            c[p][e] = cn[e];
            cs += cn[e]; cq += cn[e] * cn[e];
        }
#pragma unroll
        for (int off = 32; off > 0; off >>= 1) {
            cs += __shfl_xor(cs, off, 64);
            cq += __shfl_xor(cq, off, 64);
        }
        const float mu = cs * (1.f / 512.f);
        const float rs = rsqrtf(cq * (1.f / 512.f) - mu * mu + 1e-5f);
        const float4 la = *(const float4*)&lng[2048 + e0];
        const float4 lc = *(const float4*)&lng[2048 + e0 + 4];
        const float4 pa = *(const float4*)&lnb[2048 + e0];
        const float4 pc = *(const float4*)&lnb[2048 + e0 + 4];
        const float lgc[8] = {la.x, la.y, la.z, la.w, lc.x, lc.y, lc.z, lc.w};
        const float lbc[8] = {pa.x, pa.y, pa.z, pa.w, pc.x, pc.y, pc.z, pc.w};
        float hv[8];
#pragma unroll
        for (int e = 0; e < 8; ++e)
            hv[e] = act[3][e] * tanhf((cn[e] - mu) * rs * lgc[e] + lbc[e]);
        float4 h0v; h0v.x = hv[0]; h0v.y = hv[1]; h0v.z = hv[2]; h0v.w = hv[3];
        float4 h1v; h1v.x = hv[4]; h1v.y = hv[5]; h1v.z = hv[6]; h1v.w = hv[7];
        *(float4*)&inTh[bi * BSTR + e0]     = h0v;
        *(float4*)&inTh[bi * BSTR + e0 + 4] = h1v;
        if (wf) {   // final states (t==TT-1, bg==0 only)
            *(float4*)&fH[bi * 512 + e0]     = h0v;
            *(float4*)&fH[bi * 512 + e0 + 4] = h1v;
            float4 c0v; c0v.x = cn[0]; c0v.y = cn[1]; c0v.z = cn[2]; c0v.w = cn[3];
            float4 c1v; c1v.x = cn[4]; c1v.y = cn[5]; c1v.z = cn[6]; c1v.w = cn[7];
            *(float4*)&fC[bi * 512 + e0]     = c0v;
            *(float4*)&fC[bi * 512 + e0 + 4] = c1v;
        }
    }
}

__global__ __launch_bounds__(NTHR, 1)
void LayerNormLSTMStack_55508157333865_kernel(
    const float* __restrict__ x,
    const float* __restrict__ W0, const float* __restrict__ gb0,
    const float* __restrict__ lng0, const float* __restrict__ lnb0,
    const float* __restrict__ W1, const float* __restrict__ gb1,
    const float* __restrict__ lng1, const float* __restrict__ lnb1,
    const float* __restrict__ hwW, const float* __restrict__ hwb,
    float* __restrict__ out, float* __restrict__ ws)
{
    __shared__ __align__(16) float inT[8 * BSTR];   // 48 KB: [bi][ x | h0 | h1 ]
    __shared__ __align__(16) float zr[4 * 512];     // 8 KB per-wave K-partials
    __shared__ float hwred[256];
    __shared__ float hwz_l[128];                    // [bi][16] local highway z

    const int tid = threadIdx.x;
    const int grp = blockIdx.x >> 5;        // batch group (8 rows)
    const int bg  = blockIdx.x & 31;        // slot in group
    const int bb0 = grp * 8;
    const int r = tid & 63, bq = tid >> 6;
    const int R0 = bg * 64;                 // this block's 64 GEMV rows
    const int wv = tid >> 6, ln = tid & 63; // cell: wave / lane

    const float4* w0t = (const float4*)(ws + W0T4_OFF);
    const float4* w1t = (const float4*)(ws + W1T4_OFF);
    float* z0g = ws + Z0_OFF + grp * 16384;
    float* z1g = ws + Z1_OFF + grp * 16384;
    unsigned* gfl = (unsigned*)ws + FLG_OFF + grp * 1024;

    float c0[2][8], c1[2][8];
#pragma unroll
    for (int p = 0; p < 2; ++p)
#pragma unroll
        for (int e = 0; e < 8; ++e) { c0[p][e] = 0.f; c1[p][e] = 0.f; }

    unsigned ph = 0;
    const size_t OUT_SZ = (size_t)BB * TT * HH;
    float* fH0 = out + OUT_SZ +          (size_t)bb0 * 512;
    float* fH1 = out + OUT_SZ + 32768 +  (size_t)bb0 * 512;
    float* fC0 = out + OUT_SZ + 65536 +  (size_t)bb0 * 512;
    float* fC1 = out + OUT_SZ + 98304 +  (size_t)bb0 * 512;
    const int sbi = tid >> 5, part = tid & 31;   // staging: row sbi, lane part (16 floats)

    // ================= prologue: stage [x(0)|0|0]; gemv0(0); B1 =================
    {
        const float* xp = x + ((size_t)(bb0 + sbi) * TT + 0) * DD + part * 16;
        float* d = &inT[sbi * BSTR + part * 16];
        *(float4*)(d)      = *(const float4*)(xp);
        *(float4*)(d + 4)  = *(const float4*)(xp + 4);
        *(float4*)(d + 8)  = *(const float4*)(xp + 8);
        *(float4*)(d + 12) = *(const float4*)(xp + 12);
        const float4 zz = make_float4(0.f, 0.f, 0.f, 0.f);
        float* dh0 = &inT[sbi * BSTR + 512 + part * 16];
        *(float4*)(dh0) = zz; *(float4*)(dh0 + 4) = zz; *(float4*)(dh0 + 8) = zz; *(float4*)(dh0 + 12) = zz;
        float* dh1 = &inT[sbi * BSTR + 1024 + part * 16];
        *(float4*)(dh1) = zz; *(float4*)(dh1 + 4) = zz; *(float4*)(dh1 + 8) = zz; *(float4*)(dh1 + 12) = zz;
    }
    __syncthreads();
    {
        float z0, z1;
        gemv_k4u(w0t, inT, 0, zr, bq, r, R0 + r, z0, z1);
        stg_cg(z0g + (size_t)bq * 2048 + R0 + r, z0);
        stg_cg(z0g + (size_t)(bq + 4) * 2048 + R0 + r, z1);
    }
    group_barrier(gfl, ++ph, bg, tid);

    for (int t = 0; t < TT; ++t) {
        const bool more = (t + 1 < TT);
        const bool wf = (!more) && (bg == 0);

        // ===== cell0(t) — redundant, wave-local; writes h0(t) into inT =====
        cellW(z0g, gb0, lng0, lnb0, c0, inT + 512, wv, ln, wf, fH0, fC0);
        __syncthreads();

        // ===== gemv1(t): K = [h0(t)|h1(t-1)] =====
        {
            float z0, z1;
            gemv_k4u(w1t, inT, 512, zr, bq, r, R0 + r, z0, z1);
            stg_cg(z1g + (size_t)bq * 2048 + R0 + r, z0);
            stg_cg(z1g + (size_t)(bq + 4) * 2048 + R0 + r, z1);
        }
        // ===== highway rows [bg*16,+16) x 8 batches off h0(t) =====
        {
            const int rh = tid & 15, bi = (tid >> 4) & 7, hf = tid >> 7;
            const float* wr = hwW + (size_t)(bg * 16 + rh) * 512 + hf * 256;
            const float* ibh = &inT[bi * BSTR + 512 + hf * 256];
            float acc = 0.f;
#pragma unroll 8
            for (int k = 0; k < 256; k += 4) {
                const float4 wvv = *(const float4*)&wr[k];
                const float4 iv = *(const float4*)&ibh[k];
                acc += wvv.x * iv.x + wvv.y * iv.y + wvv.z * iv.z + wvv.w * iv.w;
            }
            hwred[tid] = acc;
            __syncthreads();
            if (tid < 128) hwz_l[tid] = hwred[tid] + hwred[tid + 128];
        }
        group_barrier(gfl, ++ph, bg, tid);    // z1(t) visible

        // ===== issue x(t+1) loads early (hide HBM under cell1) =====
        float4 xr0, xr1, xr2, xr3;
        if (more) {
            const float* xp = x + ((size_t)(bb0 + sbi) * TT + (t + 1)) * DD + part * 16;
            xr0 = *(const float4*)(xp);
            xr1 = *(const float4*)(xp + 4);
            xr2 = *(const float4*)(xp + 8);
            xr3 = *(const float4*)(xp + 12);
        }

        // ===== cell1(t) — redundant; writes h1(t) into inT =====
        cellW(z1g, gb1, lng1, lnb1, c1, inT + 1024, wv, ln, wf, fH1, fC1);
        if (more) {
            float* d = &inT[sbi * BSTR + part * 16];
            *(float4*)(d)      = xr0;
            *(float4*)(d + 4)  = xr1;
            *(float4*)(d + 8)  = xr2;
            *(float4*)(d + 12) = xr3;
        }
        __syncthreads();

        // ===== out(t): this block's 16-column slice, all local =====
        if (tid < 128) {
            const int bi = tid >> 4, rh = tid & 15;
            const int j = bg * 16 + rh;
            const float gt = 1.f / (1.f + expf(-(hwz_l[tid] + hwb[j])));
            const float h1v = inT[bi * BSTR + 1024 + j];
            const float h0v = inT[bi * BSTR + 512 + j];
            out[((size_t)(bb0 + bi) * TT + t) * HH + j] = gt * h1v + (1.f - gt) * h0v;
        }

        // ===== gemv0(t+1): K = [x(t+1)|h0(t)] =====
        if (more) {
            float z0, z1;
            gemv_k4u(w0t, inT, 0, zr, bq, r, R0 + r, z0, z1);
            stg_cg(z0g + (size_t)bq * 2048 + R0 + r, z0);
            stg_cg(z0g + (size_t)(bq + 4) * 2048 + R0 + r, z1);
        }
        group_barrier(gfl, ++ph, bg, tid);    // z0(t+1) visible
    } // t
}

extern "C" void kernel_launch(void* const* d_in, const int* in_sizes, int n_in,
                              void* d_out, int out_size, void* d_ws, size_t ws_size,
                              hipStream_t stream)
{
    (void)in_sizes; (void)n_in; (void)out_size; (void)ws_size;
    const float* x    = (const float*)d_in[0];
    const float* W0   = (const float*)d_in[1];
    const float* b0   = (const float*)d_in[2];
    const float* lng0 = (const float*)d_in[3];
    const float* lnb0 = (const float*)d_in[4];
    const float* W1   = (const float*)d_in[5];
    const float* b1   = (const float*)d_in[6];
    const float* lng1 = (const float*)d_in[7];
    const float* lnb1 = (const float*)d_in[8];
    const float* hwW  = (const float*)d_in[9];
    const float* hwb  = (const float*)d_in[10];
    float* out = (float*)d_out;
    float* ws  = (float*)d_ws;

    ln_lstm_init_kernel<<<dim3(256), dim3(256), 0, stream>>>(W0, W1, ws);
    LayerNormLSTMStack_55508157333865_kernel<<<dim3(NBLK), dim3(NTHR), 0, stream>>>(
        x, W0, b0, lng0, lnb0, W1, b1, lng1, lnb1, hwW, hwb, out, ws);
}